// Round 8
// baseline (485.207 us; speedup 1.0000x reference)
//
#include <hip/hip_runtime.h>

#define NTAG 64
#define SOS_T 61
#define EOS_T 62
#define BB 512
#define SS 1024
#define RPW 16
#define LOG2E 1.4426950408889634f
#define LN2   0.6931471805599453f

typedef float  f32x4  __attribute__((ext_vector_type(4)));
typedef int    i32x4  __attribute__((ext_vector_type(4)));
typedef short  bf16x8 __attribute__((ext_vector_type(8)));

__device__ __forceinline__ short bf16rne(float v) {
    unsigned u = __float_as_uint(v);
    u += 0x7fffu + ((u >> 16) & 1u);
    return (short)(u >> 16);
}

#define CVTPK(D, LO, HI) asm("v_cvt_pk_bf16_f32 %0, %1, %2" : "=v"(D) : "v"(LO), "v"(HI))
#define SWAP32(X, Y) asm("v_permlane32_swap_b32 %0, %1" : "+v"(X), "+v"(Y))
#define SWAP16(X, Y) asm("v_permlane16_swap_b32 %0, %1" : "+v"(X), "+v"(Y))

// Repack one r-pair of two X tiles (f32, D-layout) into two B-frag dwords.
// Derivation: dest chunk k elem e at lane(q,c) = X[32k+8q+e][c]; src x[t][r] at
// lane(q',c) = X[16t+4q'+r][c]. cvt_pk then permlane32+16 swaps realize the
// (t,q')->(q,e) group permutation exactly (verified element-wise).
#define PACK_PAIR(XA, XB, RA, RB, LOW, HIGH) do {                            \
    int p0_, p1_;                                                            \
    CVTPK(p0_, (XA)[RA], (XA)[RB]);                                          \
    CVTPK(p1_, (XB)[RA], (XB)[RB]);                                          \
    SWAP32(p0_, p1_);                                                        \
    SWAP16(p0_, p1_);                                                        \
    LOW = p0_; HIGH = p1_;                                                   \
} while (0)

#define PACKB() do {                                                         \
    PACK_PAIR(x0, x1, 0, 1, b0i[0], b0i[2]);                                 \
    PACK_PAIR(x0, x1, 2, 3, b0i[1], b0i[3]);                                 \
    PACK_PAIR(x2, x3, 0, 1, b1i[0], b1i[2]);                                 \
    PACK_PAIR(x2, x3, 2, 3, b1i[1], b1i[3]);                                 \
} while (0)

// exact per-row (per batch column) pow2 rescale; Mf += e
#define RESCALE() do {                                                       \
    f32x4 m4_;                                                               \
    _Pragma("unroll")                                                        \
    for (int r_ = 0; r_ < 4; ++r_)                                           \
        m4_[r_] = fmaxf(fmaxf(x0[r_], x1[r_]), fmaxf(x2[r_], x3[r_]));       \
    float mx_ = fmaxf(fmaxf(m4_[0], m4_[1]), fmaxf(m4_[2], m4_[3]));         \
    mx_ = fmaxf(mx_, __shfl_xor(mx_, 16));                                   \
    mx_ = fmaxf(mx_, __shfl_xor(mx_, 32));                                   \
    int ee_ = ((__float_as_int(mx_) >> 23) & 255) - 127;                     \
    float scl_ = __int_as_float((127 - ee_) << 23);                          \
    x0 *= scl_; x1 *= scl_; x2 *= scl_; x3 *= scl_;                          \
    Mf += (float)ee_;                                                        \
} while (0)

#define LOADSLOT(S, T) do {                                                  \
    int tc_ = (T) > SS - 1 ? SS - 1 : (T);                                   \
    size_t bi_ = rb16 + (size_t)tc_ * 16 + q;                                \
    er[S][0] = emb4[bi_ + 0];                                                \
    er[S][1] = emb4[bi_ + 4];                                                \
    er[S][2] = emb4[bi_ + 8];                                                \
    er[S][3] = emb4[bi_ + 12];                                               \
    mr[S] = mkb[tc_];                                                        \
} while (0)

// One step: X <- (expT^T . X) * exp(em_t), masked, opt. rescale, repack B.
#define MSTEP(S, RESC) do {                                                  \
    bf16x8 B0_, B1_;                                                         \
    __builtin_memcpy(&B0_, &b0i, 16);                                        \
    __builtin_memcpy(&B1_, &b1i, 16);                                        \
    f32x4 d0_ = __builtin_amdgcn_mfma_f32_16x16x32_bf16(af00, B0_, Z4, 0,0,0); \
    f32x4 d1_ = __builtin_amdgcn_mfma_f32_16x16x32_bf16(af10, B0_, Z4, 0,0,0); \
    f32x4 d2_ = __builtin_amdgcn_mfma_f32_16x16x32_bf16(af20, B0_, Z4, 0,0,0); \
    f32x4 d3_ = __builtin_amdgcn_mfma_f32_16x16x32_bf16(af30, B0_, Z4, 0,0,0); \
    d0_ = __builtin_amdgcn_mfma_f32_16x16x32_bf16(af01, B1_, d0_, 0,0,0);    \
    d1_ = __builtin_amdgcn_mfma_f32_16x16x32_bf16(af11, B1_, d1_, 0,0,0);    \
    d2_ = __builtin_amdgcn_mfma_f32_16x16x32_bf16(af21, B1_, d2_, 0,0,0);    \
    d3_ = __builtin_amdgcn_mfma_f32_16x16x32_bf16(af31, B1_, d3_, 0,0,0);    \
    f32x4 f0_, f1_, f2_, f3_;                                                \
    _Pragma("unroll")                                                        \
    for (int r_ = 0; r_ < 4; ++r_) {                                         \
        f0_[r_] = exp2f(er[S][0][r_] * LOG2E);                               \
        f1_[r_] = exp2f(er[S][1][r_] * LOG2E);                               \
        f2_[r_] = exp2f(er[S][2][r_] * LOG2E);                               \
        f3_[r_] = exp2f(er[S][3][r_] * LOG2E);                               \
    }                                                                        \
    float mk_ = mr[S];                                                       \
    if (__all(mk_ != 0.0f)) {                                                \
        x0 = d0_ * f0_; x1 = d1_ * f1_; x2 = d2_ * f2_; x3 = d3_ * f3_;      \
    } else {                                                                 \
        bool lv_ = (mk_ != 0.0f);                                            \
        _Pragma("unroll")                                                    \
        for (int r_ = 0; r_ < 4; ++r_) {                                     \
            x0[r_] = lv_ ? d0_[r_] * f0_[r_] : x0[r_];                       \
            x1[r_] = lv_ ? d1_[r_] * f1_[r_] : x1[r_];                       \
            x2[r_] = lv_ ? d2_[r_] * f2_[r_] : x2[r_];                       \
            x3[r_] = lv_ ? d3_[r_] * f3_[r_] : x3[r_];                       \
        }                                                                    \
    }                                                                        \
    if (RESC) RESCALE();                                                     \
    PACKB();                                                                 \
} while (0)

__global__ __launch_bounds__(64) void crf_nll_kernel(
    const float* __restrict__ emissions,  // [B,S,64]
    const int*   __restrict__ tags,       // [B,S]
    const float* __restrict__ mask,       // [B,S]
    const float* __restrict__ trans,      // [64,64]
    float* __restrict__ out)              // [1]
{
    const int lane = threadIdx.x;
    const int c = lane & 15;              // batch row within wave
    const int q = lane >> 4;              // k/m lane-group
    const int row = blockIdx.x * RPW + c;

    __shared__ __align__(16) float T_lds[NTAG * NTAG];
    const float4* tg4 = (const float4*)trans;
    float4* tl4 = (float4*)T_lds;
#pragma unroll
    for (int i = 0; i < 16; ++i) tl4[i * 64 + lane] = tg4[i * 64 + lane];
    __syncthreads();

    // A-frags: af[mt][kc][e] = bf16(exp(T[32kc+8q+e][16mt+c]))  (expT^T tiles)
    bf16x8 af00, af01, af10, af11, af20, af21, af30, af31;
#pragma unroll
    for (int e = 0; e < 8; ++e) {
        af00[e] = bf16rne(exp2f(T_lds[( 0 + 8*q + e)*NTAG + ( 0 + c)] * LOG2E));
        af01[e] = bf16rne(exp2f(T_lds[(32 + 8*q + e)*NTAG + ( 0 + c)] * LOG2E));
        af10[e] = bf16rne(exp2f(T_lds[( 0 + 8*q + e)*NTAG + (16 + c)] * LOG2E));
        af11[e] = bf16rne(exp2f(T_lds[(32 + 8*q + e)*NTAG + (16 + c)] * LOG2E));
        af20[e] = bf16rne(exp2f(T_lds[( 0 + 8*q + e)*NTAG + (32 + c)] * LOG2E));
        af21[e] = bf16rne(exp2f(T_lds[(32 + 8*q + e)*NTAG + (32 + c)] * LOG2E));
        af30[e] = bf16rne(exp2f(T_lds[( 0 + 8*q + e)*NTAG + (48 + c)] * LOG2E));
        af31[e] = bf16rne(exp2f(T_lds[(32 + 8*q + e)*NTAG + (48 + c)] * LOG2E));
    }

    const float* emb  = emissions + (size_t)row * SS * NTAG;
    const f32x4* emb4 = (const f32x4*)emissions;
    const size_t rb16 = (size_t)row * SS * 16;
    const int*   tgb  = tags + (size_t)row * SS;
    const float* mkb  = mask + (size_t)row * SS;

    // ---- gold-path score + msum: lane (q,c) covers t = q, q+4, ... of row c ----
    float scp = 0.f, msp = 0.f;
#pragma unroll 4
    for (int k = 0; k < SS / 4; ++k) {
        int t = 4 * k + q;
        int tg = tgb[t];
        float m = mkb[t];
        msp += m;
        float e = emb[t * NTAG + tg];
        if (t == 0) {
            scp += T_lds[SOS_T * NTAG + tg] + e;
        } else {
            int tp = tgb[t - 1];
            scp += m * (e + T_lds[tp * NTAG + tg]);
        }
    }
    scp += __shfl_xor(scp, 16); scp += __shfl_xor(scp, 32);
    msp += __shfl_xor(msp, 16); msp += __shfl_xor(msp, 32);
    int last_idx = (int)(msp + 0.5f) - 1;
    int last_tag = tgb[last_idx];
    float sc_row = scp + T_lds[last_tag * NTAG + EOS_T];

    // ---- X init at t=0 (D layout: lane(q,c) reg r of tile tt = tag 16tt+4q+r) ----
    f32x4 x0, x1, x2, x3;
#pragma unroll
    for (int r = 0; r < 4; ++r) {
        int tg0 =  0 + 4*q + r, tg1 = 16 + 4*q + r;
        int tg2 = 32 + 4*q + r, tg3 = 48 + 4*q + r;
        x0[r] = exp2f((T_lds[SOS_T*NTAG + tg0] + emb[tg0]) * LOG2E);
        x1[r] = exp2f((T_lds[SOS_T*NTAG + tg1] + emb[tg1]) * LOG2E);
        x2[r] = exp2f((T_lds[SOS_T*NTAG + tg2] + emb[tg2]) * LOG2E);
        x3[r] = exp2f((T_lds[SOS_T*NTAG + tg3] + emb[tg3]) * LOG2E);
    }
    float Mf = 0.f;
    RESCALE();

    i32x4 b0i, b1i;
    PACKB();

    const f32x4 Z4 = {0.f, 0.f, 0.f, 0.f};

    // ---- emission/mask prefetch ring, depth 8 steps ----
    f32x4 er[8][4];
    float mr[8];
#pragma unroll
    for (int s = 0; s < 8; ++s) LOADSLOT(s, 1 + s);

    // ---- main recursion: 127 groups of 8 (t = 1..1016), then 7-step tail ----
#pragma unroll 1
    for (int tb = 1; tb <= SS - 15; tb += 8) {
        MSTEP(0, false); LOADSLOT(0, tb + 8);
        MSTEP(1, false); LOADSLOT(1, tb + 9);
        MSTEP(2, false); LOADSLOT(2, tb + 10);
        MSTEP(3, false); LOADSLOT(3, tb + 11);
        MSTEP(4, false); LOADSLOT(4, tb + 12);
        MSTEP(5, false); LOADSLOT(5, tb + 13);
        MSTEP(6, false); LOADSLOT(6, tb + 14);
        MSTEP(7, true);  LOADSLOT(7, tb + 15);
    }
    {   // tail: t = 1017..1023
        MSTEP(0, false);
        MSTEP(1, false);
        MSTEP(2, false);
        MSTEP(3, false);
        MSTEP(4, false);
        MSTEP(5, false);
        MSTEP(6, false);
    }

    // ---- finalize: log_z[c] = (log2(sum_tag X[tag][c]*expT[tag][EOS]) + Mf)*ln2 ----
    float v = 0.f;
#pragma unroll
    for (int r = 0; r < 4; ++r) {
        v += x0[r] * exp2f(T_lds[( 0 + 4*q + r) * NTAG + EOS_T] * LOG2E);
        v += x1[r] * exp2f(T_lds[(16 + 4*q + r) * NTAG + EOS_T] * LOG2E);
        v += x2[r] * exp2f(T_lds[(32 + 4*q + r) * NTAG + EOS_T] * LOG2E);
        v += x3[r] * exp2f(T_lds[(48 + 4*q + r) * NTAG + EOS_T] * LOG2E);
    }
    v += __shfl_xor(v, 16); v += __shfl_xor(v, 32);
    float logz = (log2f(v) + Mf) * LN2;
    float nll = logz - sc_row;      // replicated 4x across q groups
#pragma unroll
    for (int o = 1; o < 64; o <<= 1) nll += __shfl_xor(nll, o);
    if (lane == 0) atomicAdd(out, nll * 0.25f);
}

extern "C" void kernel_launch(void* const* d_in, const int* in_sizes, int n_in,
                              void* d_out, int out_size, void* d_ws, size_t ws_size,
                              hipStream_t stream) {
    const float* emissions = (const float*)d_in[0];
    const int*   tags      = (const int*)d_in[1];
    const float* mask      = (const float*)d_in[2];
    const float* trans     = (const float*)d_in[3];
    float* out = (float*)d_out;

    hipMemsetAsync(out, 0, sizeof(float), stream);
    crf_nll_kernel<<<dim3(BB / RPW), dim3(64), 0, stream>>>(emissions, tags, mask, trans, out);
}

// Round 9
// 324.770 us; speedup vs baseline: 1.4940x; 1.4940x over previous
//
#include <hip/hip_runtime.h>

#define NTAG 64
#define SOS_T 61
#define EOS_T 62
#define BB 512
#define SS 1024
#define RPW 16
#define LOG2E 1.4426950408889634f
#define LN2   0.6931471805599453f
#define WS_NEED ((size_t)BB * SS * NTAG * 2)   // 64 MB bf16 E buffer

typedef float  f32x4  __attribute__((ext_vector_type(4)));
typedef int    i32x2  __attribute__((ext_vector_type(2)));
typedef int    i32x4  __attribute__((ext_vector_type(4)));
typedef short  bf16x8 __attribute__((ext_vector_type(8)));

__device__ __forceinline__ short bf16rne(float v) {
    unsigned u = __float_as_uint(v);
    u += 0x7fffu + ((u >> 16) & 1u);
    return (short)(u >> 16);
}

#define CVTPK(D, LO, HI) asm("v_cvt_pk_bf16_f32 %0, %1, %2" : "=v"(D) : "v"(LO), "v"(HI))
#define SWAP32(X, Y) asm("v_permlane32_swap_b32 %0, %1" : "+v"(X), "+v"(Y))
#define SWAP16(X, Y) asm("v_permlane16_swap_b32 %0, %1" : "+v"(X), "+v"(Y))

// ---------------- pass 1: E[t][row][tag] = bf16(exp(em[row][t][tag])) ----------------
__global__ __launch_bounds__(256) void exp_pass(const float* __restrict__ em,
                                                short* __restrict__ E) {
    size_t g = (size_t)blockIdx.x * 256 + threadIdx.x;   // g < 512*1024*8
    int s = (int)(g & 7);
    size_t rt = g >> 3;                                  // t*512 + row
    int row = (int)(rt & (BB - 1));
    int t = (int)(rt >> 9);
    const f32x4* in = (const f32x4*)(em + ((size_t)row * SS + t) * NTAG + 8 * s);
    f32x4 a = in[0], b = in[1];
    float e0 = exp2f(a[0] * LOG2E), e1 = exp2f(a[1] * LOG2E);
    float e2 = exp2f(a[2] * LOG2E), e3 = exp2f(a[3] * LOG2E);
    float e4 = exp2f(b[0] * LOG2E), e5 = exp2f(b[1] * LOG2E);
    float e6 = exp2f(b[2] * LOG2E), e7 = exp2f(b[3] * LOG2E);
    int d0, d1, d2, d3;
    CVTPK(d0, e0, e1); CVTPK(d1, e2, e3); CVTPK(d2, e4, e5); CVTPK(d3, e6, e7);
    i32x4 o = {d0, d1, d2, d3};
    *(i32x4*)((char*)E + g * 16) = o;   // (t*512+row)*128 + 16s -> tags 8s..8s+7
}

// ---------------- pass 2: MFMA scan (16 rows per wave, 32 waves) ----------------
// Repack one r-pair of two X tiles (f32, D-layout) into two B-frag dwords.
// (verified element-wise on HW in round 8: passed with absmax 0)
#define PACK_PAIR(XA, XB, RA, RB, LOW, HIGH) do {                            \
    int p0_, p1_;                                                            \
    CVTPK(p0_, (XA)[RA], (XA)[RB]);                                          \
    CVTPK(p1_, (XB)[RA], (XB)[RB]);                                          \
    SWAP32(p0_, p1_);                                                        \
    SWAP16(p0_, p1_);                                                        \
    LOW = p0_; HIGH = p1_;                                                   \
} while (0)

#define PACKB() do {                                                         \
    PACK_PAIR(x0, x1, 0, 1, b0i[0], b0i[2]);                                 \
    PACK_PAIR(x0, x1, 2, 3, b0i[1], b0i[3]);                                 \
    PACK_PAIR(x2, x3, 0, 1, b1i[0], b1i[2]);                                 \
    PACK_PAIR(x2, x3, 2, 3, b1i[1], b1i[3]);                                 \
} while (0)

#define RESCALE() do {                                                       \
    f32x4 m4_;                                                               \
    _Pragma("unroll")                                                        \
    for (int r_ = 0; r_ < 4; ++r_)                                           \
        m4_[r_] = fmaxf(fmaxf(x0[r_], x1[r_]), fmaxf(x2[r_], x3[r_]));       \
    float mx_ = fmaxf(fmaxf(m4_[0], m4_[1]), fmaxf(m4_[2], m4_[3]));         \
    mx_ = fmaxf(mx_, __shfl_xor(mx_, 16));                                   \
    mx_ = fmaxf(mx_, __shfl_xor(mx_, 32));                                   \
    int ee_ = ((__float_as_int(mx_) >> 23) & 255) - 127;                     \
    float scl_ = __int_as_float((127 - ee_) << 23);                          \
    x0 *= scl_; x1 *= scl_; x2 *= scl_; x3 *= scl_;                          \
    Mf += (float)ee_;                                                        \
} while (0)

#define STEPCORE(F0_, F1_, F2_, F3_, MK, RESC) do {                          \
    bf16x8 B0_, B1_;                                                         \
    __builtin_memcpy(&B0_, &b0i, 16);                                        \
    __builtin_memcpy(&B1_, &b1i, 16);                                        \
    f32x4 d0_ = __builtin_amdgcn_mfma_f32_16x16x32_bf16(af00, B0_, Z4, 0,0,0); \
    f32x4 d1_ = __builtin_amdgcn_mfma_f32_16x16x32_bf16(af10, B0_, Z4, 0,0,0); \
    f32x4 d2_ = __builtin_amdgcn_mfma_f32_16x16x32_bf16(af20, B0_, Z4, 0,0,0); \
    f32x4 d3_ = __builtin_amdgcn_mfma_f32_16x16x32_bf16(af30, B0_, Z4, 0,0,0); \
    d0_ = __builtin_amdgcn_mfma_f32_16x16x32_bf16(af01, B1_, d0_, 0,0,0);    \
    d1_ = __builtin_amdgcn_mfma_f32_16x16x32_bf16(af11, B1_, d1_, 0,0,0);    \
    d2_ = __builtin_amdgcn_mfma_f32_16x16x32_bf16(af21, B1_, d2_, 0,0,0);    \
    d3_ = __builtin_amdgcn_mfma_f32_16x16x32_bf16(af31, B1_, d3_, 0,0,0);    \
    float mk_ = (MK);                                                        \
    if (__all(mk_ != 0.0f)) {                                                \
        x0 = d0_ * F0_; x1 = d1_ * F1_; x2 = d2_ * F2_; x3 = d3_ * F3_;      \
    } else {                                                                 \
        bool lv_ = (mk_ != 0.0f);                                            \
        _Pragma("unroll")                                                    \
        for (int r_ = 0; r_ < 4; ++r_) {                                     \
            x0[r_] = lv_ ? d0_[r_] * F0_[r_] : x0[r_];                       \
            x1[r_] = lv_ ? d1_[r_] * F1_[r_] : x1[r_];                       \
            x2[r_] = lv_ ? d2_[r_] * F2_[r_] : x2[r_];                       \
            x3[r_] = lv_ ? d3_[r_] * F3_[r_] : x3[r_];                       \
        }                                                                    \
    }                                                                        \
    if (RESC) RESCALE();                                                     \
    PACKB();                                                                 \
} while (0)

#define UNPK(F_, V_) do {                                                    \
    F_[0] = __int_as_float((V_).x << 16);                                    \
    F_[1] = __int_as_float((V_).x & (int)0xffff0000);                        \
    F_[2] = __int_as_float((V_).y << 16);                                    \
    F_[3] = __int_as_float((V_).y & (int)0xffff0000);                        \
} while (0)

#define MSTEP_P(S, RESC) do {                                                \
    f32x4 f0_, f1_, f2_, f3_;                                                \
    UNPK(f0_, er2[S][0]); UNPK(f1_, er2[S][1]);                              \
    UNPK(f2_, er2[S][2]); UNPK(f3_, er2[S][3]);                              \
    STEPCORE(f0_, f1_, f2_, f3_, mr[S], RESC);                               \
} while (0)

#define MSTEP_R(S, RESC) do {                                                \
    f32x4 f0_, f1_, f2_, f3_;                                                \
    _Pragma("unroll")                                                        \
    for (int r_ = 0; r_ < 4; ++r_) {                                         \
        f0_[r_] = exp2f(er4[S][0][r_] * LOG2E);                              \
        f1_[r_] = exp2f(er4[S][1][r_] * LOG2E);                              \
        f2_[r_] = exp2f(er4[S][2][r_] * LOG2E);                              \
        f3_[r_] = exp2f(er4[S][3][r_] * LOG2E);                              \
    }                                                                        \
    STEPCORE(f0_, f1_, f2_, f3_, mr[S], RESC);                               \
} while (0)

#define LOADSLOT_P(S, T) do {                                                \
    int tc_ = (T) > SS - 1 ? SS - 1 : (T);                                   \
    const char* pp_ = Eb + (size_t)tc_ * (BB * 128) + lanebase;              \
    er2[S][0] = *(const i32x2*)(pp_ + 0);                                    \
    er2[S][1] = *(const i32x2*)(pp_ + 32);                                   \
    er2[S][2] = *(const i32x2*)(pp_ + 64);                                   \
    er2[S][3] = *(const i32x2*)(pp_ + 96);                                   \
    mr[S] = mkb[tc_];                                                        \
} while (0)

#define LOADSLOT_R(S, T) do {                                                \
    int tc_ = (T) > SS - 1 ? SS - 1 : (T);                                   \
    size_t bi_ = rb16 + (size_t)tc_ * 16 + q;                                \
    er4[S][0] = emb4[bi_ + 0];                                               \
    er4[S][1] = emb4[bi_ + 4];                                               \
    er4[S][2] = emb4[bi_ + 8];                                               \
    er4[S][3] = emb4[bi_ + 12];                                              \
    mr[S] = mkb[tc_];                                                        \
} while (0)

template <bool PRE>
__global__ __launch_bounds__(64, 1) void crf_scan(
    const float* __restrict__ emissions,  // [B,S,64]
    const int*   __restrict__ tags,       // [B,S]
    const float* __restrict__ mask,       // [B,S]
    const float* __restrict__ trans,      // [64,64]
    const short* __restrict__ E,          // [S,B,64] bf16 exp(em) (PRE only)
    float* __restrict__ out)              // [1]
{
    const int lane = threadIdx.x;
    const int c = lane & 15;              // batch row within wave
    const int q = lane >> 4;              // k/m lane-group
    const int row = blockIdx.x * RPW + c;

    __shared__ __align__(16) float T_lds[NTAG * NTAG];
    const float4* tg4 = (const float4*)trans;
    float4* tl4 = (float4*)T_lds;
#pragma unroll
    for (int i = 0; i < 16; ++i) tl4[i * 64 + lane] = tg4[i * 64 + lane];
    __syncthreads();

    // A-frags: af[mt][kc][e] = bf16(exp(T[32kc+8q+e][16mt+c]))  (expT^T tiles)
    bf16x8 af00, af01, af10, af11, af20, af21, af30, af31;
#pragma unroll
    for (int e = 0; e < 8; ++e) {
        af00[e] = bf16rne(exp2f(T_lds[( 0 + 8*q + e)*NTAG + ( 0 + c)] * LOG2E));
        af01[e] = bf16rne(exp2f(T_lds[(32 + 8*q + e)*NTAG + ( 0 + c)] * LOG2E));
        af10[e] = bf16rne(exp2f(T_lds[( 0 + 8*q + e)*NTAG + (16 + c)] * LOG2E));
        af11[e] = bf16rne(exp2f(T_lds[(32 + 8*q + e)*NTAG + (16 + c)] * LOG2E));
        af20[e] = bf16rne(exp2f(T_lds[( 0 + 8*q + e)*NTAG + (32 + c)] * LOG2E));
        af21[e] = bf16rne(exp2f(T_lds[(32 + 8*q + e)*NTAG + (32 + c)] * LOG2E));
        af30[e] = bf16rne(exp2f(T_lds[( 0 + 8*q + e)*NTAG + (48 + c)] * LOG2E));
        af31[e] = bf16rne(exp2f(T_lds[(32 + 8*q + e)*NTAG + (48 + c)] * LOG2E));
    }

    const float* emb  = emissions + (size_t)row * SS * NTAG;
    const f32x4* emb4 = (const f32x4*)emissions;
    const size_t rb16 = (size_t)row * SS * 16;
    const int*   tgb  = tags + (size_t)row * SS;
    const float* mkb  = mask + (size_t)row * SS;
    const char*  Eb   = (const char*)E;
    const size_t lanebase = (size_t)row * 128 + 8 * q;

    // ---- gold-path score + msum: lane (q,c) covers t = q, q+4, ... of row c ----
    float scp = 0.f, msp = 0.f;
#pragma unroll 4
    for (int k = 0; k < SS / 4; ++k) {
        int t = 4 * k + q;
        int tg = tgb[t];
        float m = mkb[t];
        msp += m;
        float e = emb[t * NTAG + tg];
        if (t == 0) {
            scp += T_lds[SOS_T * NTAG + tg] + e;
        } else {
            int tp = tgb[t - 1];
            scp += m * (e + T_lds[tp * NTAG + tg]);
        }
    }
    scp += __shfl_xor(scp, 16); scp += __shfl_xor(scp, 32);
    msp += __shfl_xor(msp, 16); msp += __shfl_xor(msp, 32);
    int last_idx = (int)(msp + 0.5f) - 1;
    int last_tag = tgb[last_idx];
    float sc_row = scp + T_lds[last_tag * NTAG + EOS_T];

    // ---- X init at t=0 (D layout: lane(q,c) reg r of tile tt = tag 16tt+4q+r) ----
    f32x4 x0, x1, x2, x3;
#pragma unroll
    for (int r = 0; r < 4; ++r) {
        int tg0 =  0 + 4*q + r, tg1 = 16 + 4*q + r;
        int tg2 = 32 + 4*q + r, tg3 = 48 + 4*q + r;
        x0[r] = exp2f((T_lds[SOS_T*NTAG + tg0] + emb[tg0]) * LOG2E);
        x1[r] = exp2f((T_lds[SOS_T*NTAG + tg1] + emb[tg1]) * LOG2E);
        x2[r] = exp2f((T_lds[SOS_T*NTAG + tg2] + emb[tg2]) * LOG2E);
        x3[r] = exp2f((T_lds[SOS_T*NTAG + tg3] + emb[tg3]) * LOG2E);
    }
    float Mf = 0.f;
    RESCALE();

    i32x4 b0i, b1i;
    PACKB();

    const f32x4 Z4 = {0.f, 0.f, 0.f, 0.f};

    // ---- prefetch rings, depth 8 steps ----
    i32x2 er2[8][4];    // PRE: bf16 exp(em) pairs
    f32x4 er4[8][4];    // !PRE: raw f32 emissions
    float mr[8];

    if constexpr (PRE) {
#pragma unroll
        for (int s = 0; s < 8; ++s) LOADSLOT_P(s, 1 + s);
#pragma unroll 1
        for (int tb = 1; tb <= SS - 15; tb += 8) {
            MSTEP_P(0, false); LOADSLOT_P(0, tb + 8);
            MSTEP_P(1, false); LOADSLOT_P(1, tb + 9);
            MSTEP_P(2, false); LOADSLOT_P(2, tb + 10);
            MSTEP_P(3, false); LOADSLOT_P(3, tb + 11);
            MSTEP_P(4, false); LOADSLOT_P(4, tb + 12);
            MSTEP_P(5, false); LOADSLOT_P(5, tb + 13);
            MSTEP_P(6, false); LOADSLOT_P(6, tb + 14);
            MSTEP_P(7, true);  LOADSLOT_P(7, tb + 15);
        }
        MSTEP_P(0, false);
        MSTEP_P(1, false);
        MSTEP_P(2, false);
        MSTEP_P(3, false);
        MSTEP_P(4, false);
        MSTEP_P(5, false);
        MSTEP_P(6, false);
    } else {
#pragma unroll
        for (int s = 0; s < 8; ++s) LOADSLOT_R(s, 1 + s);
#pragma unroll 1
        for (int tb = 1; tb <= SS - 15; tb += 8) {
            MSTEP_R(0, false); LOADSLOT_R(0, tb + 8);
            MSTEP_R(1, false); LOADSLOT_R(1, tb + 9);
            MSTEP_R(2, false); LOADSLOT_R(2, tb + 10);
            MSTEP_R(3, false); LOADSLOT_R(3, tb + 11);
            MSTEP_R(4, false); LOADSLOT_R(4, tb + 12);
            MSTEP_R(5, false); LOADSLOT_R(5, tb + 13);
            MSTEP_R(6, false); LOADSLOT_R(6, tb + 14);
            MSTEP_R(7, true);  LOADSLOT_R(7, tb + 15);
        }
        MSTEP_R(0, false);
        MSTEP_R(1, false);
        MSTEP_R(2, false);
        MSTEP_R(3, false);
        MSTEP_R(4, false);
        MSTEP_R(5, false);
        MSTEP_R(6, false);
    }

    // ---- finalize: log_z[c] = (log2(sum_tag X[tag][c]*expT[tag][EOS]) + Mf)*ln2 ----
    float v = 0.f;
#pragma unroll
    for (int r = 0; r < 4; ++r) {
        v += x0[r] * exp2f(T_lds[( 0 + 4*q + r) * NTAG + EOS_T] * LOG2E);
        v += x1[r] * exp2f(T_lds[(16 + 4*q + r) * NTAG + EOS_T] * LOG2E);
        v += x2[r] * exp2f(T_lds[(32 + 4*q + r) * NTAG + EOS_T] * LOG2E);
        v += x3[r] * exp2f(T_lds[(48 + 4*q + r) * NTAG + EOS_T] * LOG2E);
    }
    v += __shfl_xor(v, 16); v += __shfl_xor(v, 32);
    float logz = (log2f(v) + Mf) * LN2;
    float nll = logz - sc_row;      // replicated 4x across q groups
#pragma unroll
    for (int o = 1; o < 64; o <<= 1) nll += __shfl_xor(nll, o);
    if (lane == 0) atomicAdd(out, nll * 0.25f);
}

extern "C" void kernel_launch(void* const* d_in, const int* in_sizes, int n_in,
                              void* d_out, int out_size, void* d_ws, size_t ws_size,
                              hipStream_t stream) {
    const float* emissions = (const float*)d_in[0];
    const int*   tags      = (const int*)d_in[1];
    const float* mask      = (const float*)d_in[2];
    const float* trans     = (const float*)d_in[3];
    float* out = (float*)d_out;

    hipMemsetAsync(out, 0, sizeof(float), stream);
    if (ws_size >= WS_NEED) {
        short* E = (short*)d_ws;
        exp_pass<<<dim3(BB * SS * 8 / 256), dim3(256), 0, stream>>>(emissions, E);
        crf_scan<true><<<dim3(BB / RPW), dim3(64), 0, stream>>>(
            emissions, tags, mask, trans, E, out);
    } else {
        crf_scan<false><<<dim3(BB / RPW), dim3(64), 0, stream>>>(
            emissions, tags, mask, trans, nullptr, out);
    }
}